// Round 2
// baseline (415.800 us; speedup 1.0000x reference)
//
#include <hip/hip_runtime.h>

// MultiCellLSTM: B=4096 chains, H=64, T=512, 3 cell types by t%4 (0,2,1,2).
// Block = 16 batch rows, 1024 threads = 16 waves = (gate g 0..3) x (slice s 0..3).
// Each wave computes ONE 16x16 MFMA tile (gate g, h-cols s*16..s*16+15) with
// wave-uniform activation (sig/tanh unified via per-wave constants), writes
// activated gates to LDS act[g][m][h]; after a barrier each lane owns ONE cell
// (m = wid, h = lane) and does the cx/hx update. 2 barriers/step, 4 waves/SIMD.

typedef __attribute__((ext_vector_type(8))) short short8v;
typedef __attribute__((ext_vector_type(4))) float float4v;

template <int N> struct IC { static constexpr int value = N; };

#define STRIDE 104       // bf16 elems per A row; 16B-aligned frags (c*208+q*16)
#define AMS 65           // act m-stride (dwords), padded vs 64
#define AGS (16 * AMS)   // act gate-stride = 1040 dwords

#if __has_builtin(__builtin_amdgcn_exp2f)
#define EXP2F(x) __builtin_amdgcn_exp2f(x)
#else
#define EXP2F(x) exp2f(x)
#endif
#if __has_builtin(__builtin_amdgcn_rcpf)
#define RCPF(x) __builtin_amdgcn_rcpf(x)
#else
#define RCPF(x) (1.0f / (x))
#endif

__device__ __forceinline__ short f2bf(float f) {
  union { float f; unsigned u; } v; v.f = f;
  unsigned r = v.u + 0x7FFFu + ((v.u >> 16) & 1u);  // RNE
  return (short)(r >> 16);
}
__device__ __forceinline__ float fsig(float x) {
  float e = EXP2F(x * -1.4426950408889634f);
  return RCPF(1.0f + e);
}
__device__ __forceinline__ float ftanh(float x) {
  float e = EXP2F(x * -2.8853900817779268f);
  return __builtin_fmaf(2.0f, RCPF(1.0f + e), -1.0f);
}

__global__ __launch_bounds__(1024, 4) void mlstm_kernel(
    const float* __restrict__ x1, const float* __restrict__ x2,
    const float* __restrict__ x3,
    const float* __restrict__ Wi3, const float* __restrict__ Wh3,
    const float* __restrict__ bi3, const float* __restrict__ bh3,
    const float* __restrict__ Wi2, const float* __restrict__ Wh2,
    const float* __restrict__ bi2, const float* __restrict__ bh2,
    const float* __restrict__ Wi1, const float* __restrict__ Wh1,
    const float* __restrict__ bi1, const float* __restrict__ bh1,
    const float* __restrict__ Wout, const float* __restrict__ bout,
    float* __restrict__ out) {
  __shared__ __attribute__((aligned(16))) short Ab[16 * STRIDE];
  __shared__ float actb[4 * AGS];
  __shared__ short x1b[16 * 512];
  __shared__ short x2b[16 * 256];
  __shared__ short x3b[16 * 128];

  const int tid = threadIdx.x;   // 0..1023
  const int wid = tid >> 6;      // 0..15
  const int lane = tid & 63;
  const int q = lane >> 4;       // quad
  const int c = lane & 15;
  const int g = wid >> 2;        // gate (i,f,g,o)
  const int s = wid & 3;         // h-slice
  const int R0 = blockIdx.x << 4;

  // ---- preload x into LDS as bf16 ----
  for (int idx = tid; idx < 16 * 512; idx += 1024) {
    int m = idx >> 9, t = idx & 511;
    x1b[idx] = f2bf(x1[(size_t)(R0 + m) * 512 + t]);
  }
  for (int idx = tid; idx < 16 * 256; idx += 1024) {
    int m = idx >> 8, t = idx & 255;
    x2b[idx] = f2bf(x2[(size_t)(R0 + m) * 256 + t]);
  }
  for (int idx = tid; idx < 16 * 128; idx += 1024) {
    int m = idx >> 7, t = idx & 127;
    x3b[idx] = f2bf(x3[(size_t)(R0 + m) * 128 + t]);
  }

  // ---- init A: hx=0, col67 = 1.0 (bias), rest 0; write x(t=0) from global ----
  for (int idx = tid; idx < 16 * STRIDE; idx += 1024) {
    int col = idx % STRIDE;
    Ab[idx] = (col == 67) ? (short)0x3F80 : (short)0;
  }
  if (wid == 0) {
    if (lane < 16) {
      Ab[lane * STRIDE + 64] = f2bf(x1[(size_t)(R0 + lane) * 512]);
    } else if (lane < 32) {
      int m = lane - 16;
      Ab[m * STRIDE + 65] = f2bf(x2[(size_t)(R0 + m) * 256]);
    } else if (lane < 48) {
      int m = lane - 32;
      Ab[m * STRIDE + 66] = f2bf(x3[(size_t)(R0 + m) * 128]);
    }
  }

  // ---- pack this wave's B-fragments: n = g*64 + s*16 + c ----
  // B[k][n]: k = kf*32 + q*8 + j. k0..63 = Wh; k64..66 = Wi (zero-pad); k67 = bias.
  short8v wf[3][3];
  {
    const float* WhA[3] = {Wh3, Wh2, Wh1};
    const float* WiA[3] = {Wi3, Wi2, Wi1};
    const float* biA[3] = {bi3, bi2, bi1};
    const float* bhA[3] = {bh3, bh2, bh1};
    const int wdt[3] = {3, 2, 1};
    const int n = g * 64 + s * 16 + c;
#pragma unroll
    for (int ty = 0; ty < 3; ++ty) {
#pragma unroll
      for (int kf = 0; kf < 2; ++kf) {
        short8v v;
#pragma unroll
        for (int j = 0; j < 8; ++j)
          v[j] = f2bf(WhA[ty][n * 64 + kf * 32 + q * 8 + j]);
        wf[ty][kf] = v;
      }
      short8v v2 = {0, 0, 0, 0, 0, 0, 0, 0};
      if (q == 0) {
#pragma unroll
        for (int j = 0; j < 3; ++j)
          if (j < wdt[ty]) v2[j] = f2bf(WiA[ty][n * wdt[ty] + j]);
        v2[3] = f2bf(biA[ty][n] + bhA[ty][n]);
      }
      wf[ty][2] = v2;
    }
  }

  const float wout = Wout[lane];  // f32, coalesced per wave
  const float bo = bout[0];

  // wave-uniform activation constants: act(x) = kA * rcp(1 + exp2(kS*x)) + kB
  const float kS = (g == 2) ? -2.8853900817779268f : -1.4426950408889634f;
  const float kA = (g == 2) ? 2.0f : 1.0f;
  const float kB = (g == 2) ? -1.0f : 0.0f;

  // addressing
  const short* afp = Ab + c * STRIDE + q * 8;          // A-frag: m=c, k=q*8+j (16B aligned)
  float* awp = actb + g * AGS + (q * 4) * AMS + s * 16 + c;  // act write (4 rows, stride AMS)
  const float* arp = actb + wid * AMS + lane;          // act read: cell (m=wid, h=lane)
  short* hxp = Ab + wid * STRIDE + lane;               // hx write

  __syncthreads();

  float cx = 0.f;
  float hv = 0.f;

  auto stepf = [&](auto tyc, int t) {
    constexpr int TY = decltype(tyc)::value;
    // ---- phase 1: MFMA + gate activation ----
    short8v a0 = *(const short8v*)(afp);
    short8v a1 = *(const short8v*)(afp + 32);
    short8v a2 = *(const short8v*)(afp + 64);
    float4v acc = {0.f, 0.f, 0.f, 0.f};
    acc = __builtin_amdgcn_mfma_f32_16x16x32_bf16(a0, wf[TY][0], acc, 0, 0, 0);
    acc = __builtin_amdgcn_mfma_f32_16x16x32_bf16(a1, wf[TY][1], acc, 0, 0, 0);
    acc = __builtin_amdgcn_mfma_f32_16x16x32_bf16(a2, wf[TY][2], acc, 0, 0, 0);
#pragma unroll
    for (int r = 0; r < 4; ++r) {
      float e = EXP2F(acc[r] * kS);
      awp[r * AMS] = __builtin_fmaf(kA, RCPF(1.0f + e), kB);
    }
    __syncthreads();
    // ---- phase 2: cell update (1 cell/lane: m=wid, h=lane) ----
    float si = arp[0 * AGS];
    float sf = arp[1 * AGS];
    float tg = arp[2 * AGS];
    float so = arp[3 * AGS];
    float ncx = __builtin_fmaf(sf, cx, si * tg);
    cx = ncx;
    hv = so * ftanh(ncx);
    *hxp = f2bf(hv);
    // stage x(t+1) into A (cols 64..66); stale values are weight-masked to 0
    int tn = t + 1;
    if (tn > 511) tn = 511;
    if (wid == 0) {
      if (lane < 16) {
        x1b[0] = x1b[0];  // no-op keep structure simple
        Ab[lane * STRIDE + 64] = x1b[lane * 512 + tn];
      } else if (lane < 32) {
        int m = lane - 16;
        Ab[m * STRIDE + 65] = x2b[m * 256 + (tn >> 1)];
      } else if (lane < 48) {
        int m = lane - 32;
        Ab[m * STRIDE + 66] = x3b[m * 128 + (tn >> 2)];
      }
    }
    __syncthreads();
  };

  // t%4 pattern: 0->ty0, 1->ty2, 2->ty1, 3->ty2
  for (int t4 = 0; t4 < 512; t4 += 4) {
    stepf(IC<0>{}, t4);
    stepf(IC<2>{}, t4 + 1);
    stepf(IC<1>{}, t4 + 2);
    stepf(IC<2>{}, t4 + 3);
  }

  // ---- output: out[R0+wid] = sig(sum_h hv*Wout[h] + b) via wave reduction ----
  float p = hv * wout;
#pragma unroll
  for (int o = 1; o < 64; o <<= 1) p += __shfl_xor(p, o, 64);
  if (lane == 0) out[R0 + wid] = fsig(p + bo);
}

extern "C" void kernel_launch(void* const* d_in, const int* in_sizes, int n_in,
                              void* d_out, int out_size, void* d_ws,
                              size_t ws_size, hipStream_t stream) {
  const float* x1 = (const float*)d_in[0];
  const float* x2 = (const float*)d_in[1];
  const float* x3 = (const float*)d_in[2];
  const float* Wi3 = (const float*)d_in[3];
  const float* Wh3 = (const float*)d_in[4];
  const float* bi3 = (const float*)d_in[5];
  const float* bh3 = (const float*)d_in[6];
  const float* Wi2 = (const float*)d_in[7];
  const float* Wh2 = (const float*)d_in[8];
  const float* bi2 = (const float*)d_in[9];
  const float* bh2 = (const float*)d_in[10];
  const float* Wi1 = (const float*)d_in[11];
  const float* Wh1 = (const float*)d_in[12];
  const float* bi1 = (const float*)d_in[13];
  const float* bh1 = (const float*)d_in[14];
  const float* Wout = (const float*)d_in[15];
  const float* bout = (const float*)d_in[16];
  float* out = (float*)d_out;

  hipLaunchKernelGGL(mlstm_kernel, dim3(256), dim3(1024), 0, stream,
                     x1, x2, x3, Wi3, Wh3, bi3, bh3, Wi2, Wh2, bi2, bh2,
                     Wi1, Wh1, bi1, bh1, Wout, bout, out);
}

// Round 3
// 333.231 us; speedup vs baseline: 1.2478x; 1.2478x over previous
//
#include <hip/hip_runtime.h>

// MultiCellLSTM: B=4096 chains, H=64, T=512, 3 cell types by t%4 (0,2,1,2).
// R3: R1 structure (block = 16 rows, 4 waves; wave w owns all 4 gate-tiles of
// h-cols 16w..16w+15 -> cell update register-local; ONE barrier/step), plus:
//  - a2 frag (k=64..95) holds only x+zeros, built in registers from x LDS
//    (3 broadcast ds_read_u16) -> no staging writes, A-stride 104->72,
//    frag reads 6xb64 -> 2xb128
//  - bias as f32 MFMA C-input (free, more precise)
//  - activation scale folded into weights: y = W'.x, act = rcp(1+exp2(y))
//    (W' = W * -log2e for i,f,o rows; * -2log2e for g rows)
//  - x buffers stride-padded (516/260/132) for conflict-free per-step reads.
// Stale x2/x3 reads at off-phase steps are masked by zero weight columns
// (type-2/1 Wi cols are zero), matching the reference's zero-concat.

typedef __attribute__((ext_vector_type(8))) short short8v;
typedef __attribute__((ext_vector_type(4))) float float4v;

template <int N> struct IC { static constexpr int value = N; };

#define AST 72   // shorts per A row: 64 hx + 8 pad; 16B-aligned frags (144c+16q)
#define XS1 516  // x1 row stride (shorts): dword-stride 258 mod 32 = 2 -> conflict-free
#define XS2 260
#define XS3 132

#if __has_builtin(__builtin_amdgcn_exp2f)
#define EXP2F(x) __builtin_amdgcn_exp2f(x)
#else
#define EXP2F(x) exp2f(x)
#endif
#if __has_builtin(__builtin_amdgcn_rcpf)
#define RCPF(x) __builtin_amdgcn_rcpf(x)
#else
#define RCPF(x) (1.0f / (x))
#endif

#define NL2E -1.4426950408889634f   // -log2(e)
#define NL2E2 -2.8853900817779268f  // -2*log2(e)

__device__ __forceinline__ short f2bf(float f) {
  union { float f; unsigned u; } v; v.f = f;
  unsigned r = v.u + 0x7FFFu + ((v.u >> 16) & 1u);  // RNE
  return (short)(r >> 16);
}
__device__ __forceinline__ float bf2f(short h) {
  union { float f; unsigned u; } v;
  v.u = ((unsigned)(unsigned short)h) << 16;
  return v.f;
}
// act on pre-scaled y: sigmoid(x) = rcp(1+exp2(y)), y = x*NL2E
__device__ __forceinline__ float rcp1p(float y) {
  return RCPF(1.0f + EXP2F(y));
}
__device__ __forceinline__ float fsig(float x) { return rcp1p(x * NL2E); }
__device__ __forceinline__ float ftanh(float x) {
  return __builtin_fmaf(2.0f, rcp1p(x * NL2E2), -1.0f);
}

__global__ __launch_bounds__(256, 1) void mlstm_kernel(
    const float* __restrict__ x1, const float* __restrict__ x2,
    const float* __restrict__ x3,
    const float* __restrict__ Wi3, const float* __restrict__ Wh3,
    const float* __restrict__ bi3, const float* __restrict__ bh3,
    const float* __restrict__ Wi2, const float* __restrict__ Wh2,
    const float* __restrict__ bi2, const float* __restrict__ bh2,
    const float* __restrict__ Wi1, const float* __restrict__ Wh1,
    const float* __restrict__ bi1, const float* __restrict__ bh1,
    const float* __restrict__ Wout, const float* __restrict__ bout,
    float* __restrict__ out) {
  __shared__ __attribute__((aligned(16))) short Ab0[16 * AST];
  __shared__ __attribute__((aligned(16))) short Ab1[16 * AST];
  __shared__ short x1b[16 * XS1];
  __shared__ short x2b[16 * XS2];
  __shared__ short x3b[16 * XS3];

  const int tid = threadIdx.x;  // 0..255
  const int w = tid >> 6;       // wave = h-col slice 0..3
  const int lane = tid & 63;
  const int q = lane >> 4;
  const int c = lane & 15;
  const int R0 = blockIdx.x << 4;

  // ---- preload x into LDS as bf16 (padded strides) ----
  for (int idx = tid; idx < 16 * 512; idx += 256) {
    int m = idx >> 9, t = idx & 511;
    x1b[m * XS1 + t] = f2bf(x1[(size_t)(R0 + m) * 512 + t]);
  }
  for (int idx = tid; idx < 16 * 256; idx += 256) {
    int m = idx >> 8, t = idx & 255;
    x2b[m * XS2 + t] = f2bf(x2[(size_t)(R0 + m) * 256 + t]);
  }
  for (int idx = tid; idx < 16 * 128; idx += 256) {
    int m = idx >> 7, t = idx & 127;
    x3b[m * XS3 + t] = f2bf(x3[(size_t)(R0 + m) * 128 + t]);
  }
  // ---- A buffers: hx(t=0) = 0 ----
  for (int idx = tid; idx < 16 * AST; idx += 256) {
    Ab0[idx] = 0;
    Ab1[idx] = 0;
  }

  // ---- pack scaled weight fragments (per wave: tiles g=0..3, n = g*64+16w+c) ----
  // whs[ty][g][kf]: B[k][n] = s_g * Wh[n][k], k = kf*32 + q*8 + j
  // wix[ty][g]    : k = 64+8q+j -> q==0,j<3: s_g * Wi[n][j], else 0
  // bias4[ty][g]  : f32 splat of s_g * (bi[n]+bh[n])  (MFMA C-input)
  short8v whs[3][4][2];
  short8v wix[3][4];
  float4v bias4[3][4];
  {
    const float* WhA[3] = {Wh3, Wh2, Wh1};
    const float* WiA[3] = {Wi3, Wi2, Wi1};
    const float* biA[3] = {bi3, bi2, bi1};
    const float* bhA[3] = {bh3, bh2, bh1};
    const int wdt[3] = {3, 2, 1};
#pragma unroll
    for (int ty = 0; ty < 3; ++ty) {
#pragma unroll
      for (int g = 0; g < 4; ++g) {
        const float sg = (g == 2) ? NL2E2 : NL2E;
        const int n = g * 64 + 16 * w + c;
#pragma unroll
        for (int kf = 0; kf < 2; ++kf) {
          short8v v;
#pragma unroll
          for (int j = 0; j < 8; ++j)
            v[j] = f2bf(sg * WhA[ty][n * 64 + kf * 32 + q * 8 + j]);
          whs[ty][g][kf] = v;
        }
        short8v v2 = {0, 0, 0, 0, 0, 0, 0, 0};
        if (q == 0) {
#pragma unroll
          for (int j = 0; j < 3; ++j)
            if (j < wdt[ty]) v2[j] = f2bf(sg * WiA[ty][n * wdt[ty] + j]);
        }
        wix[ty][g] = v2;
        float b = sg * (biA[ty][n] + bhA[ty][n]);
        float4v bv = {b, b, b, b};
        bias4[ty][g] = bv;
      }
    }
  }

  // addressing
  const int afo = c * AST + q * 8;         // A-frag base: m=c, k=q*8+j
  const int hwo = (4 * q) * AST + 16 * w + c;  // hx write base (rows 4q+r)
  const int x1o = c * XS1;                 // x row = c (broadcast across q)
  const int x2o = c * XS2;
  const int x3o = c * XS3;

  __syncthreads();

  float cx[4] = {0.f, 0.f, 0.f, 0.f};

  auto stepf = [&](auto tyc, int t, const short* rbuf, short* wbuf) {
    constexpr int TY = decltype(tyc)::value;
    // x(t) frag: only q==0/j<3 weights are nonzero; other lanes' (finite)
    // values are multiplied by zero. Broadcast reads (4 lanes/addr).
    short hx1 = x1b[x1o + t];
    short hx2 = x2b[x2o + (t >> 1)];
    short hx3 = x3b[x3o + (t >> 2)];
    short8v a2 = {hx1, hx2, hx3, 0, 0, 0, 0, 0};
    short8v a0 = *(const short8v*)(rbuf + afo);
    short8v a1 = *(const short8v*)(rbuf + afo + 32);

    float4v acc[4];
#pragma unroll
    for (int g = 0; g < 4; ++g) {
      float4v z = bias4[TY][g];
      z = __builtin_amdgcn_mfma_f32_16x16x32_bf16(a0, whs[TY][g][0], z, 0, 0, 0);
      z = __builtin_amdgcn_mfma_f32_16x16x32_bf16(a1, whs[TY][g][1], z, 0, 0, 0);
      z = __builtin_amdgcn_mfma_f32_16x16x32_bf16(a2, wix[TY][g], z, 0, 0, 0);
      acc[g] = z;
    }

    short* hb = wbuf + hwo;
#pragma unroll
    for (int r = 0; r < 4; ++r) {
      float si = rcp1p(acc[0][r]);                              // sigmoid(i)
      float sf = rcp1p(acc[1][r]);                              // sigmoid(f)
      float tg = __builtin_fmaf(2.0f, rcp1p(acc[2][r]), -1.0f); // tanh(g)
      float so = rcp1p(acc[3][r]);                              // sigmoid(o)
      float ncx = __builtin_fmaf(sf, cx[r], si * tg);
      cx[r] = ncx;
      float hv = so * ftanh(ncx);
      hb[r * AST] = f2bf(hv);
    }
    __syncthreads();
  };

  // t%4 -> type: 0->0, 1->2, 2->1, 3->2
  for (int t4 = 0; t4 < 512; t4 += 4) {
    stepf(IC<0>{}, t4, Ab0, Ab1);
    stepf(IC<2>{}, t4 + 1, Ab1, Ab0);
    stepf(IC<1>{}, t4 + 2, Ab0, Ab1);
    stepf(IC<2>{}, t4 + 3, Ab1, Ab0);
  }
  // final hx (after 512 steps) is in Ab0

  if (tid < 16) {
    float s = bout[0];
    const short* hr = Ab0 + tid * AST;
#pragma unroll
    for (int k = 0; k < 64; ++k)
      s = __builtin_fmaf(bf2f(hr[k]), Wout[k], s);
    out[R0 + tid] = fsig(s);
  }
}

extern "C" void kernel_launch(void* const* d_in, const int* in_sizes, int n_in,
                              void* d_out, int out_size, void* d_ws,
                              size_t ws_size, hipStream_t stream) {
  const float* x1 = (const float*)d_in[0];
  const float* x2 = (const float*)d_in[1];
  const float* x3 = (const float*)d_in[2];
  const float* Wi3 = (const float*)d_in[3];
  const float* Wh3 = (const float*)d_in[4];
  const float* bi3 = (const float*)d_in[5];
  const float* bh3 = (const float*)d_in[6];
  const float* Wi2 = (const float*)d_in[7];
  const float* Wh2 = (const float*)d_in[8];
  const float* bi2 = (const float*)d_in[9];
  const float* bh2 = (const float*)d_in[10];
  const float* Wi1 = (const float*)d_in[11];
  const float* Wh1 = (const float*)d_in[12];
  const float* bi1 = (const float*)d_in[13];
  const float* bh1 = (const float*)d_in[14];
  const float* Wout = (const float*)d_in[15];
  const float* bout = (const float*)d_in[16];
  float* out = (float*)d_out;

  hipLaunchKernelGGL(mlstm_kernel, dim3(256), dim3(256), 0, stream,
                     x1, x2, x3, Wi3, Wh3, bi3, bh3, Wi2, Wh2, bi2, bh2,
                     Wi1, Wh1, bi1, bh1, Wout, bout, out);
}